// Round 13
// baseline (145.804 us; speedup 1.0000x reference)
//
#include <hip/hip_runtime.h>

#define NB_B  2
#define NB_Q  10000
#define NB_D  256
#define NB_NH 8
#define NB_NL 4
#define NB_NP 4
#define NB_HD 32
#define NB_S  21760   // 128*128 + 64*64 + 32*32 + 16*16
#define MQ    20000   // B*Q
#define MQB   313     // ceil(20000/64)
#define NVB   1360    // (B*S/64)*2  vproj blocks
#define NCB   939     // MQB*3       coords blocks

#define ASTR  536     // A oct stride in halfs
#define BSTR  1048    // B oct stride in halfs

typedef _Float16 half8 __attribute__((ext_vector_type(8)));
typedef float f32x4 __attribute__((ext_vector_type(4)));

// ---------------------------------------------------------------------------
// Prep: transpose + fp16-convert weights to Wt[n][k] (k-major, 256 k each).
// ---------------------------------------------------------------------------
__global__ __launch_bounds__(256) void k_prepw(const float* __restrict__ Wv,
                                               const float* __restrict__ Ws,
                                               const float* __restrict__ Wa,
                                               const float* __restrict__ Wo,
                                               _Float16* __restrict__ Wvt,
                                               _Float16* __restrict__ Wsat,
                                               _Float16* __restrict__ Wot)
{
    const int k = threadIdx.x;
    const int nc = blockIdx.x;
    if (nc < 256) {
        Wvt[nc * 256 + k] = (_Float16)Wv[k * 256 + nc];
    } else if (nc < 640) {
        const int n = nc - 256;
        const float v = (n < 256) ? Ws[k * 256 + n] : Wa[k * 128 + (n - 256)];
        Wsat[n * 256 + k] = (_Float16)v;
    } else {
        const int n = nc - 640;
        Wot[n * 256 + k] = (_Float16)Wo[k * 256 + n];
    }
}

// ---------------------------------------------------------------------------
// k_front: co-launched vproj [0,NVB) + coords [NVB,NVB+NCB).
// BM=64, BN=128, BK=32, 2-buf LDS. WRITE-EARLY + REG PREFETCH DIST-2:
//   it(kt) = [ W(tile kt+1 -> buf^1); L(tile kt+3 -> regs); R(frags kt); MFMA; barrier ]
// Load->use slack = 2 iterations; reg loads survive the barrier (no vmcnt drain).
// ---------------------------------------------------------------------------
__global__ __launch_bounds__(256) void k_front(const float* __restrict__ value,
                                               const float* __restrict__ query,
                                               const _Float16* __restrict__ Wvt,
                                               const _Float16* __restrict__ Wsat,
                                               const float* __restrict__ refp,
                                               const float* __restrict__ bv,
                                               const float* __restrict__ bs,
                                               const float* __restrict__ ba,
                                               _Float16* __restrict__ vt,
                                               float* __restrict__ sx,
                                               float* __restrict__ sy,
                                               float* __restrict__ sw)
{
    __shared__ __align__(16) _Float16 Ah[2][4 * ASTR];
    __shared__ __align__(16) _Float16 Bh[2][4 * BSTR];
    __shared__ float rp[64][8];            // 2 KB (coords only)

    const int t = threadIdx.x;
    const int lane = t & 63, w = t >> 6;
    const int bid = blockIdx.x;
    const bool isv = (bid < NVB);

    int row0, n0;
    const float* Asrc;
    const _Float16* Bsrc;
    if (isv) {
        n0 = (bid & 1) * 128;
        row0 = (bid >> 1) * 64;
        Asrc = value;
        Bsrc = Wvt;
    } else {
        const int cid = bid - NVB;
        n0 = (cid % 3) * 128;
        row0 = (cid / 3) * 64;
        Asrc = query;
        Bsrc = Wsat;
        const int i0 = row0 * 8 + t;
        rp[t >> 3][t & 7] = refp[min(i0, MQ * 8 - 1)];
        const int i1 = i0 + 256;
        rp[32 + (t >> 3)][t & 7] = refp[min(i1, MQ * 8 - 1)];
    }

    // coalesced staging maps
    const int arr = t >> 3;   // A row within 32-row half
    const int acl = t & 7;    // A float4 col within 32-k tile
    const int bnn = t >> 2;   // B n within 64-row half
    const int bcl = t & 3;    // B oct col

    const float* gA0;
    const float* gA1;
    {
        int r0i = row0 + arr, r1i = row0 + 32 + arr;
        if (!isv) { r0i = min(r0i, MQ - 1); r1i = min(r1i, MQ - 1); }
        gA0 = Asrc + (size_t)r0i * 256 + acl * 4;
        gA1 = Asrc + (size_t)r1i * 256 + acl * 4;
    }
    const _Float16* gB0 = Bsrc + (size_t)(n0 + bnn) * 256 + bcl * 8;
    const _Float16* gB1 = Bsrc + (size_t)(n0 + 64 + bnn) * 256 + bcl * 8;

    // two register tile-sets (compile-time indexed in unrolled loop)
    float4 ar0[2], ar1[2];
    uint4  br0[2], br1[2];
#define LOADT(rs, kt) { ar0[rs] = *reinterpret_cast<const float4*>(gA0 + (kt) * 32); \
                        ar1[rs] = *reinterpret_cast<const float4*>(gA1 + (kt) * 32); \
                        br0[rs] = *reinterpret_cast<const uint4*>(gB0 + (kt) * 32);  \
                        br1[rs] = *reinterpret_cast<const uint4*>(gB1 + (kt) * 32); }

    const int awoff = (acl >> 1) * ASTR + arr * 8 + (acl & 1) * 4;
#define WRITET(buf, rs) { \
        union { _Float16 h[4]; uint2 u; } p0, p1; \
        p0.h[0] = (_Float16)ar0[rs].x; p0.h[1] = (_Float16)ar0[rs].y; \
        p0.h[2] = (_Float16)ar0[rs].z; p0.h[3] = (_Float16)ar0[rs].w; \
        p1.h[0] = (_Float16)ar1[rs].x; p1.h[1] = (_Float16)ar1[rs].y; \
        p1.h[2] = (_Float16)ar1[rs].z; p1.h[3] = (_Float16)ar1[rs].w; \
        *reinterpret_cast<uint2*>(&Ah[buf][awoff])          = p0.u; \
        *reinterpret_cast<uint2*>(&Ah[buf][awoff + 32 * 8]) = p1.u; \
        *reinterpret_cast<uint4*>(&Bh[buf][bcl * BSTR + bnn * 8])        = br0[rs]; \
        *reinterpret_cast<uint4*>(&Bh[buf][bcl * BSTR + (64 + bnn) * 8]) = br1[rs]; }

    f32x4 acc[4][2];
#pragma unroll
    for (int fr = 0; fr < 4; ++fr)
#pragma unroll
        for (int fc = 0; fc < 2; ++fc) acc[fr][fc] = (f32x4){0.f, 0.f, 0.f, 0.f};

    // prologue: tiles 0,1 -> regsets 0,1; tile0 -> LDS buf0; tile2 -> regset0
    LOADT(0, 0);
    LOADT(1, 1);
    WRITET(0, 0);
    LOADT(0, 2);
    __syncthreads();

    const int rowb = lane & 15;
    const int kq = lane >> 4;
#pragma unroll
    for (int kt = 0; kt < 8; ++kt) {
        const int buf = kt & 1;
        if (kt < 7) WRITET(buf ^ 1, (kt + 1) & 1);   // vmcnt leaves tile kt+2 in flight
        if (kt < 5) LOADT((kt + 1) & 1, kt + 3);

        half8 af[4], bf[2];
#pragma unroll
        for (int fr = 0; fr < 4; ++fr)
            af[fr] = *reinterpret_cast<const half8*>(&Ah[buf][kq * ASTR + (fr * 16 + rowb) * 8]);
#pragma unroll
        for (int fc = 0; fc < 2; ++fc)
            bf[fc] = *reinterpret_cast<const half8*>(&Bh[buf][kq * BSTR + (w * 32 + fc * 16 + rowb) * 8]);
#pragma unroll
        for (int fr = 0; fr < 4; ++fr)
#pragma unroll
            for (int fc = 0; fc < 2; ++fc)
                acc[fr][fc] = __builtin_amdgcn_mfma_f32_16x16x32_f16(af[fr], bf[fc], acc[fr][fc], 0, 0, 0);
        if (kt < 7) __syncthreads();
    }
#undef LOADT
#undef WRITET

    // ---- epilogues ----
    if (isv) {
        const int b = (row0 >= NB_S) ? 1 : 0;
        const int sb = row0 - b * NB_S;
#pragma unroll
        for (int fc = 0; fc < 2; ++fc) {
            const int n = n0 + w * 32 + fc * 16 + rowb;
            const int h = n >> 5, hd = n & 31;
            const float bvn = bv[n];
#pragma unroll
            for (int fr = 0; fr < 4; ++fr) {
                const f32x4 c = acc[fr][fc];
#pragma unroll
                for (int j = 0; j < 4; ++j) {
                    const int m = fr * 16 + (lane >> 4) * 4 + j;
                    vt[((size_t)((b * NB_NH + h) * NB_S + (sb + m)) << 5) + hd] = (_Float16)(c[j] + bvn);
                }
            }
        }
    } else if (n0 < 256) {
#pragma unroll
        for (int fc = 0; fc < 2; ++fc) {
            const int n = n0 + w * 32 + fc * 16 + rowb;
            const int si = n >> 1, xy = n & 1;
            const int l = (n >> 3) & 3;
            const float dim = (float)(128 >> l);
            const float bsv = bs[n];
            float* dst = xy ? sy : sx;
#pragma unroll
            for (int fr = 0; fr < 4; ++fr) {
                const f32x4 c = acc[fr][fc];
#pragma unroll
                for (int j = 0; j < 4; ++j) {
                    const int m = fr * 16 + (lane >> 4) * 4 + j;
                    if (row0 + m < MQ) {
                        const float coord = rp[m][l * 2 + xy] * dim + (c[j] + bsv) - 0.5f;
                        dst[(size_t)(row0 + m) * 128 + si] = coord;
                    }
                }
            }
        }
    } else {
#pragma unroll
        for (int fc = 0; fc < 2; ++fc) {
            const int col = w * 32 + fc * 16 + rowb;
            const float bav = ba[col];
#pragma unroll
            for (int fr = 0; fr < 4; ++fr) {
                const f32x4 c = acc[fr][fc];
#pragma unroll
                for (int j = 0; j < 4; ++j) {
                    const int m = fr * 16 + (lane >> 4) * 4 + j;
                    float v = c[j] + bav;
                    float vm = v;
                    vm = fmaxf(vm, __shfl_xor(vm, 1));
                    vm = fmaxf(vm, __shfl_xor(vm, 2));
                    vm = fmaxf(vm, __shfl_xor(vm, 4));
                    vm = fmaxf(vm, __shfl_xor(vm, 8));
                    const float e = expf(v - vm);
                    float s = e;
                    s += __shfl_xor(s, 1);
                    s += __shfl_xor(s, 2);
                    s += __shfl_xor(s, 4);
                    s += __shfl_xor(s, 8);
                    if (row0 + m < MQ)
                        sw[(size_t)(row0 + m) * 128 + col] = e / s;
                }
            }
        }
    }
}

// ---------------------------------------------------------------------------
// gather: block = (16 queries, 1 head); head = blockIdx.x & 7 (XCD locality).
// ---------------------------------------------------------------------------
__global__ __launch_bounds__(256) void k_gather(const _Float16* __restrict__ vt,
                                                const float* __restrict__ sx,
                                                const float* __restrict__ sy,
                                                const float* __restrict__ sw,
                                                _Float16* __restrict__ tmp)
{
    __shared__ int   offs[16][16][4];
    __shared__ float wts[16][16][4];
    const int t = threadIdx.x;
    const int gid = blockIdx.x;
    const int h = gid & 7;
    const int row0 = (gid >> 3) * 16;
    const int b = (row0 >= NB_Q) ? 1 : 0;

    {
        const int r = t >> 4, s = t & 15;
        const size_t ci = (size_t)(row0 + r) * 128 + h * 16 + s;
        const float x = sx[ci], y = sy[ci], w = sw[ci];
        const int l = s >> 2;
        const int dim = 128 >> l;
        const int startL = (l == 0) ? 0 : (l == 1) ? 16384 : (l == 2) ? 20480 : 21504;
        const float x0f = floorf(x), y0f = floorf(y);
        const float lx = x - x0f, ly = y - y0f;
        const int ix = (int)x0f, iy = (int)y0f;
        const int ix0 = min(max(ix, 0), dim - 1), ix1 = min(max(ix + 1, 0), dim - 1);
        const int iy0 = min(max(iy, 0), dim - 1), iy1 = min(max(iy + 1, 0), dim - 1);
        const float vx0 = (ix >= 0 && ix < dim) ? 1.f : 0.f;
        const float vx1 = (ix + 1 >= 0 && ix + 1 < dim) ? 1.f : 0.f;
        const float vy0 = (iy >= 0 && iy < dim) ? 1.f : 0.f;
        const float vy1 = (iy + 1 >= 0 && iy + 1 < dim) ? 1.f : 0.f;
        offs[r][s][0] = (startL + iy0 * dim + ix0) * (NB_HD * 2);
        offs[r][s][1] = (startL + iy0 * dim + ix1) * (NB_HD * 2);
        offs[r][s][2] = (startL + iy1 * dim + ix0) * (NB_HD * 2);
        offs[r][s][3] = (startL + iy1 * dim + ix1) * (NB_HD * 2);
        wts[r][s][0] = w * (1.f - lx) * (1.f - ly) * vx0 * vy0;
        wts[r][s][1] = w * lx * (1.f - ly) * vx1 * vy0;
        wts[r][s][2] = w * (1.f - lx) * ly * vx0 * vy1;
        wts[r][s][3] = w * lx * ly * vx1 * vy1;
    }
    __syncthreads();

    const int r = t >> 4, hd2 = t & 15;
    const char* slab = reinterpret_cast<const char*>(vt)
                     + (size_t)(b * NB_NH + h) * NB_S * (NB_HD * 2);
    const int byo = hd2 * 4;
    float ax = 0.f, ay = 0.f;
#pragma unroll
    for (int s = 0; s < 16; ++s) {
        const int4   o = *reinterpret_cast<const int4*>(&offs[r][s][0]);
        const float4 w = *reinterpret_cast<const float4*>(&wts[r][s][0]);
        union { unsigned u; _Float16 h[2]; } c0, c1, c2, c3;
        c0.u = *reinterpret_cast<const unsigned*>(slab + (o.x + byo));
        c1.u = *reinterpret_cast<const unsigned*>(slab + (o.y + byo));
        c2.u = *reinterpret_cast<const unsigned*>(slab + (o.z + byo));
        c3.u = *reinterpret_cast<const unsigned*>(slab + (o.w + byo));
        ax = fmaf(w.x, (float)c0.h[0], ax); ay = fmaf(w.x, (float)c0.h[1], ay);
        ax = fmaf(w.y, (float)c1.h[0], ax); ay = fmaf(w.y, (float)c1.h[1], ay);
        ax = fmaf(w.z, (float)c2.h[0], ax); ay = fmaf(w.z, (float)c2.h[1], ay);
        ax = fmaf(w.w, (float)c3.h[0], ax); ay = fmaf(w.w, (float)c3.h[1], ay);
    }
    union { unsigned u; _Float16 h[2]; } p;
    p.h[0] = (_Float16)ax; p.h[1] = (_Float16)ay;
    *reinterpret_cast<unsigned*>(tmp + (size_t)(row0 + r) * 256 + h * 32 + hd2 * 2) = p.u;
}

// ---------------------------------------------------------------------------
// oproj: out = tmp @ Wo + bo. BM=64, BN=128 (2-way), BK=32, 2-buf,
// write-early + reg prefetch dist-2 (same schedule as k_front).
// ---------------------------------------------------------------------------
__global__ __launch_bounds__(256) void k_oproj_mm(const _Float16* __restrict__ tmp,
                                                  const _Float16* __restrict__ Wot,
                                                  const float* __restrict__ bo,
                                                  float* __restrict__ out)
{
    __shared__ __align__(16) _Float16 Ao[2][4 * ASTR];
    __shared__ __align__(16) _Float16 Bh[2][4 * BSTR];
    const int t = threadIdx.x;
    const int lane = t & 63, w = t >> 6;
    const int bid = blockIdx.x;
    const int n0 = (bid & 1) * 128;
    const int row0 = (bid >> 1) * 64;

    const int arr = t >> 2;   // A row 0..63
    const int acl = t & 3;    // A oct
    const int bnn = t >> 2;   // B n within 64-half
    const int bcl = t & 3;    // B oct

    const _Float16* gA0 = tmp + (size_t)min(row0 + arr, MQ - 1) * 256 + acl * 8;
    const _Float16* gB0 = Wot + (size_t)(n0 + bnn) * 256 + bcl * 8;
    const _Float16* gB1 = Wot + (size_t)(n0 + 64 + bnn) * 256 + bcl * 8;

    uint4 ar[2], br0[2], br1[2];
#define LOADT(rs, kt) { ar[rs]  = *reinterpret_cast<const uint4*>(gA0 + (kt) * 32); \
                        br0[rs] = *reinterpret_cast<const uint4*>(gB0 + (kt) * 32); \
                        br1[rs] = *reinterpret_cast<const uint4*>(gB1 + (kt) * 32); }
#define WRITET(buf, rs) { \
        *reinterpret_cast<uint4*>(&Ao[buf][acl * ASTR + arr * 8])        = ar[rs]; \
        *reinterpret_cast<uint4*>(&Bh[buf][bcl * BSTR + bnn * 8])        = br0[rs]; \
        *reinterpret_cast<uint4*>(&Bh[buf][bcl * BSTR + (64 + bnn) * 8]) = br1[rs]; }

    f32x4 acc[4][2];
#pragma unroll
    for (int fr = 0; fr < 4; ++fr)
#pragma unroll
        for (int fc = 0; fc < 2; ++fc) acc[fr][fc] = (f32x4){0.f, 0.f, 0.f, 0.f};

    LOADT(0, 0);
    LOADT(1, 1);
    WRITET(0, 0);
    LOADT(0, 2);
    __syncthreads();

    const int rowb = lane & 15;
    const int kq = lane >> 4;
#pragma unroll
    for (int kt = 0; kt < 8; ++kt) {
        const int buf = kt & 1;
        if (kt < 7) WRITET(buf ^ 1, (kt + 1) & 1);
        if (kt < 5) LOADT((kt + 1) & 1, kt + 3);

        half8 af[4], bf[2];
#pragma unroll
        for (int fr = 0; fr < 4; ++fr)
            af[fr] = *reinterpret_cast<const half8*>(&Ao[buf][kq * ASTR + (fr * 16 + rowb) * 8]);
#pragma unroll
        for (int fc = 0; fc < 2; ++fc)
            bf[fc] = *reinterpret_cast<const half8*>(&Bh[buf][kq * BSTR + (w * 32 + fc * 16 + rowb) * 8]);
#pragma unroll
        for (int fr = 0; fr < 4; ++fr)
#pragma unroll
            for (int fc = 0; fc < 2; ++fc)
                acc[fr][fc] = __builtin_amdgcn_mfma_f32_16x16x32_f16(af[fr], bf[fc], acc[fr][fc], 0, 0, 0);
        if (kt < 7) __syncthreads();
    }
#undef LOADT
#undef WRITET

#pragma unroll
    for (int fc = 0; fc < 2; ++fc) {
        const int n = n0 + w * 32 + fc * 16 + rowb;
        const float bon = bo[n];
#pragma unroll
        for (int fr = 0; fr < 4; ++fr) {
            const f32x4 c = acc[fr][fc];
#pragma unroll
            for (int j = 0; j < 4; ++j) {
                const int m = fr * 16 + (lane >> 4) * 4 + j;
                if (row0 + m < MQ)
                    out[(size_t)(row0 + m) * 256 + n] = c[j] + bon;
            }
        }
    }
}

// ---------------------------------------------------------------------------
extern "C" void kernel_launch(void* const* d_in, const int* in_sizes, int n_in,
                              void* d_out, int out_size, void* d_ws, size_t ws_size,
                              hipStream_t stream)
{
    const float* query = (const float*)d_in[0];
    const float* refp  = (const float*)d_in[1];
    const float* value = (const float*)d_in[2];
    const float* Wv = (const float*)d_in[4];
    const float* bv = (const float*)d_in[5];
    const float* Ws = (const float*)d_in[6];
    const float* bs = (const float*)d_in[7];
    const float* Wa = (const float*)d_in[8];
    const float* ba = (const float*)d_in[9];
    const float* Wo = (const float*)d_in[10];
    const float* bo = (const float*)d_in[11];
    float* out = (float*)d_out;

    char* ws = (char*)d_ws;
    _Float16* vt_h  = (_Float16*)(ws + 0);          // 43520*256*2   = 22,282,240 B
    _Float16* tmp_h = (_Float16*)(ws + 22282240);   // 20000*256*2   = 10,240,000 B
    _Float16* Wvt   = (_Float16*)(ws + 32522240);   //                   131,072 B
    _Float16* Wsat  = (_Float16*)(ws + 32653312);   //                   196,608 B
    _Float16* Wot   = (_Float16*)(ws + 32849920);   //                   131,072 B
    float*    sxg   = (float*)   (ws + 32980992);   // 20000*128*4   = 10,240,000 B
    float*    syg   = (float*)   (ws + 43220992);
    float*    swg   = (float*)   (ws + 53460992);   // ends 63,700,992

    hipLaunchKernelGGL(k_prepw, dim3(896), dim3(256), 0, stream,
                       Wv, Ws, Wa, Wo, Wvt, Wsat, Wot);
    hipLaunchKernelGGL(k_front, dim3(NVB + NCB), dim3(256), 0, stream,
                       value, query, Wvt, Wsat, refp, bv, bs, ba,
                       vt_h, sxg, syg, swg);
    hipLaunchKernelGGL(k_gather, dim3(NB_B * NB_Q / 16 * NB_NH), dim3(256), 0, stream,
                       vt_h, sxg, syg, swg, tmp_h);
    hipLaunchKernelGGL(k_oproj_mm, dim3(MQB * 2), dim3(256), 0, stream,
                       tmp_h, Wot, bo, out);
}

// Round 14
// 129.735 us; speedup vs baseline: 1.1239x; 1.1239x over previous
//
#include <hip/hip_runtime.h>

#define NB_B  2
#define NB_Q  10000
#define NB_D  256
#define NB_NH 8
#define NB_NL 4
#define NB_NP 4
#define NB_HD 32
#define NB_S  21760   // 128*128 + 64*64 + 32*32 + 16*16
#define MQ    20000   // B*Q
#define MQB   313     // ceil(20000/64)
#define NVB3  680     // vproj blocks (B*S/64)
#define NCO3  313     // coords-offset blocks
#define NCL3  313     // coords-logit blocks

#define ASTR  536     // A oct stride in halfs
#define BSTR2 2056    // B oct stride in halfs: 256*8 + 8
#define BSTRO 1048    // oproj B oct stride: 128*8 + 8

typedef _Float16 half8 __attribute__((ext_vector_type(8)));
typedef float f32x4 __attribute__((ext_vector_type(4)));

// ---------------------------------------------------------------------------
// Prep: transpose + fp16-convert weights to Wt[n][k] (k-major, 256 k each).
// ---------------------------------------------------------------------------
__global__ __launch_bounds__(256) void k_prepw(const float* __restrict__ Wv,
                                               const float* __restrict__ Ws,
                                               const float* __restrict__ Wa,
                                               const float* __restrict__ Wo,
                                               _Float16* __restrict__ Wvt,
                                               _Float16* __restrict__ Wsat,
                                               _Float16* __restrict__ Wot)
{
    const int k = threadIdx.x;
    const int nc = blockIdx.x;
    if (nc < 256) {
        Wvt[nc * 256 + k] = (_Float16)Wv[k * 256 + nc];
    } else if (nc < 640) {
        const int n = nc - 256;
        const float v = (n < 256) ? Ws[k * 256 + n] : Wa[k * 128 + (n - 256)];
        Wsat[n * 256 + k] = (_Float16)v;
    } else {
        const int n = nc - 640;
        Wot[n * 256 + k] = (_Float16)Wo[k * 256 + n];
    }
}

// ---------------------------------------------------------------------------
// k_front: 3 block types, fat tiles (no N-split of A panels):
//   type 0: vproj          BM=64 x BN=256  blocks [0, 680)
//   type 1: coords-offsets BM=64 x BN=256  blocks [680, 993)
//   type 2: coords-logits  BM=64 x BN=128  blocks [993, 1306)
// R9-proven loop: WRITET(regs->LDS); LOADT(next->regs); barrier; frags; MFMA.
// Coalesced staging; 16 (8 for logits) MFMA per wave per K-step.
// ---------------------------------------------------------------------------
__global__ __launch_bounds__(256) void k_front(const float* __restrict__ value,
                                               const float* __restrict__ query,
                                               const _Float16* __restrict__ Wvt,
                                               const _Float16* __restrict__ Wsat,
                                               const float* __restrict__ refp,
                                               const float* __restrict__ bv,
                                               const float* __restrict__ bs,
                                               const float* __restrict__ ba,
                                               _Float16* __restrict__ vt,
                                               float* __restrict__ sx,
                                               float* __restrict__ sy,
                                               float* __restrict__ sw)
{
    __shared__ __align__(16) _Float16 Ah[2][4 * ASTR];    //  8,576 B
    __shared__ __align__(16) _Float16 Bh[2][4 * BSTR2];   // 32,896 B
    __shared__ float rp[64][8];                           //  2 KB

    const int t = threadIdx.x;
    const int lane = t & 63, w = t >> 6;
    const int bid = blockIdx.x;
    const int type = (bid < NVB3) ? 0 : (bid < NVB3 + NCO3) ? 1 : 2;
    const bool isv = (type == 0);

    int row0;
    const float* Asrc;
    const _Float16* Bsrc;
    if (type == 0)      { row0 = bid * 64;                 Asrc = value; Bsrc = Wvt; }
    else if (type == 1) { row0 = (bid - NVB3) * 64;        Asrc = query; Bsrc = Wsat; }
    else                { row0 = (bid - NVB3 - NCO3) * 64; Asrc = query; Bsrc = Wsat + 256 * 256; }
    const int nb  = (type == 2) ? 2 : 4;    // B 64-row groups
    const int nwd = (type == 2) ? 32 : 64;  // cols per wave

    if (type == 1) {
        const int i0 = row0 * 8 + t;
        rp[t >> 3][t & 7] = refp[min(i0, MQ * 8 - 1)];
        const int i1 = i0 + 256;
        rp[32 + (t >> 3)][t & 7] = refp[min(i1, MQ * 8 - 1)];
    }

    // coalesced staging maps (R9)
    const int arr = t >> 3;   // A row within 32-row half
    const int acl = t & 7;    // A float4 col
    const int bnn = t >> 2;   // B n within 64-row group
    const int bcl = t & 3;    // B oct col

    const float* gA0;
    const float* gA1;
    {
        int r0i = row0 + arr, r1i = row0 + 32 + arr;
        if (!isv) { r0i = min(r0i, MQ - 1); r1i = min(r1i, MQ - 1); }
        gA0 = Asrc + (size_t)r0i * 256 + acl * 4;
        gA1 = Asrc + (size_t)r1i * 256 + acl * 4;
    }
    const _Float16* gBb = Bsrc + (size_t)bnn * 256 + bcl * 8;

    float4 ar0, ar1;
    uint4  br[4];
#define LOADT(kt) { ar0 = *reinterpret_cast<const float4*>(gA0 + (kt) * 32); \
                    ar1 = *reinterpret_cast<const float4*>(gA1 + (kt) * 32); \
                    _Pragma("unroll") \
                    for (int i = 0; i < 4; ++i) \
                        if (i < nb) br[i] = *reinterpret_cast<const uint4*>(gBb + (size_t)i * 64 * 256 + (kt) * 32); }

    const int awoff = (acl >> 1) * ASTR + arr * 8 + (acl & 1) * 4;
#define WRITET(buf) { \
        union { _Float16 h[4]; uint2 u; } p0, p1; \
        p0.h[0] = (_Float16)ar0.x; p0.h[1] = (_Float16)ar0.y; \
        p0.h[2] = (_Float16)ar0.z; p0.h[3] = (_Float16)ar0.w; \
        p1.h[0] = (_Float16)ar1.x; p1.h[1] = (_Float16)ar1.y; \
        p1.h[2] = (_Float16)ar1.z; p1.h[3] = (_Float16)ar1.w; \
        *reinterpret_cast<uint2*>(&Ah[buf][awoff])          = p0.u; \
        *reinterpret_cast<uint2*>(&Ah[buf][awoff + 32 * 8]) = p1.u; \
        _Pragma("unroll") \
        for (int i = 0; i < 4; ++i) \
            if (i < nb) *reinterpret_cast<uint4*>(&Bh[buf][bcl * BSTR2 + (i * 64 + bnn) * 8]) = br[i]; }

    f32x4 acc[4][4];
#pragma unroll
    for (int fr = 0; fr < 4; ++fr)
#pragma unroll
        for (int fc = 0; fc < 4; ++fc) acc[fr][fc] = (f32x4){0.f, 0.f, 0.f, 0.f};

    LOADT(0);

    const int rowb = lane & 15;
    const int kq = lane >> 4;
#pragma unroll
    for (int kt = 0; kt < 8; ++kt) {
        const int buf = kt & 1;
        WRITET(buf);
        if (kt < 7) LOADT(kt + 1);
        __syncthreads();

        half8 af[4], bf[4];
#pragma unroll
        for (int fr = 0; fr < 4; ++fr)
            af[fr] = *reinterpret_cast<const half8*>(&Ah[buf][kq * ASTR + (fr * 16 + rowb) * 8]);
#pragma unroll
        for (int fc = 0; fc < 4; ++fc)
            if (fc * 16 < nwd)
                bf[fc] = *reinterpret_cast<const half8*>(&Bh[buf][kq * BSTR2 + (w * nwd + fc * 16 + rowb) * 8]);
#pragma unroll
        for (int fr = 0; fr < 4; ++fr)
#pragma unroll
            for (int fc = 0; fc < 4; ++fc)
                if (fc * 16 < nwd)
                    acc[fr][fc] = __builtin_amdgcn_mfma_f32_16x16x32_f16(af[fr], bf[fc], acc[fr][fc], 0, 0, 0);
        if (kt < 7) __syncthreads();
    }
#undef LOADT
#undef WRITET

    // ---- epilogues ----
    if (type == 0) {
        const int b = (row0 >= NB_S) ? 1 : 0;
        const int sb = row0 - b * NB_S;
#pragma unroll
        for (int fc = 0; fc < 4; ++fc) {
            const int n = w * 64 + fc * 16 + rowb;
            const int h = n >> 5, hd = n & 31;
            const float bvn = bv[n];
#pragma unroll
            for (int fr = 0; fr < 4; ++fr) {
                const f32x4 c = acc[fr][fc];
#pragma unroll
                for (int j = 0; j < 4; ++j) {
                    const int m = fr * 16 + (lane >> 4) * 4 + j;
                    vt[((size_t)((b * NB_NH + h) * NB_S + (sb + m)) << 5) + hd] = (_Float16)(c[j] + bvn);
                }
            }
        }
    } else if (type == 1) {
#pragma unroll
        for (int fc = 0; fc < 4; ++fc) {
            const int n = w * 64 + fc * 16 + rowb;
            const int si = n >> 1, xy = n & 1;
            const int l = (n >> 3) & 3;
            const float dim = (float)(128 >> l);
            const float bsv = bs[n];
            float* dst = xy ? sy : sx;
#pragma unroll
            for (int fr = 0; fr < 4; ++fr) {
                const f32x4 c = acc[fr][fc];
#pragma unroll
                for (int j = 0; j < 4; ++j) {
                    const int m = fr * 16 + (lane >> 4) * 4 + j;
                    if (row0 + m < MQ) {
                        const float coord = rp[m][l * 2 + xy] * dim + (c[j] + bsv) - 0.5f;
                        dst[(size_t)(row0 + m) * 128 + si] = coord;
                    }
                }
            }
        }
    } else {
#pragma unroll
        for (int fc = 0; fc < 2; ++fc) {
            const int col = w * 32 + fc * 16 + rowb;
            const float bav = ba[col];
#pragma unroll
            for (int fr = 0; fr < 4; ++fr) {
                const f32x4 c = acc[fr][fc];
#pragma unroll
                for (int j = 0; j < 4; ++j) {
                    const int m = fr * 16 + (lane >> 4) * 4 + j;
                    float v = c[j] + bav;
                    float vm = v;
                    vm = fmaxf(vm, __shfl_xor(vm, 1));
                    vm = fmaxf(vm, __shfl_xor(vm, 2));
                    vm = fmaxf(vm, __shfl_xor(vm, 4));
                    vm = fmaxf(vm, __shfl_xor(vm, 8));
                    const float e = expf(v - vm);
                    float s = e;
                    s += __shfl_xor(s, 1);
                    s += __shfl_xor(s, 2);
                    s += __shfl_xor(s, 4);
                    s += __shfl_xor(s, 8);
                    if (row0 + m < MQ)
                        sw[(size_t)(row0 + m) * 128 + col] = e / s;
                }
            }
        }
    }
}

// ---------------------------------------------------------------------------
// gather: block = (16 queries, 1 head); head = blockIdx.x & 7 (XCD locality).
// ---------------------------------------------------------------------------
__global__ __launch_bounds__(256) void k_gather(const _Float16* __restrict__ vt,
                                                const float* __restrict__ sx,
                                                const float* __restrict__ sy,
                                                const float* __restrict__ sw,
                                                _Float16* __restrict__ tmp)
{
    __shared__ int   offs[16][16][4];
    __shared__ float wts[16][16][4];
    const int t = threadIdx.x;
    const int gid = blockIdx.x;
    const int h = gid & 7;
    const int row0 = (gid >> 3) * 16;
    const int b = (row0 >= NB_Q) ? 1 : 0;

    {
        const int r = t >> 4, s = t & 15;
        const size_t ci = (size_t)(row0 + r) * 128 + h * 16 + s;
        const float x = sx[ci], y = sy[ci], w = sw[ci];
        const int l = s >> 2;
        const int dim = 128 >> l;
        const int startL = (l == 0) ? 0 : (l == 1) ? 16384 : (l == 2) ? 20480 : 21504;
        const float x0f = floorf(x), y0f = floorf(y);
        const float lx = x - x0f, ly = y - y0f;
        const int ix = (int)x0f, iy = (int)y0f;
        const int ix0 = min(max(ix, 0), dim - 1), ix1 = min(max(ix + 1, 0), dim - 1);
        const int iy0 = min(max(iy, 0), dim - 1), iy1 = min(max(iy + 1, 0), dim - 1);
        const float vx0 = (ix >= 0 && ix < dim) ? 1.f : 0.f;
        const float vx1 = (ix + 1 >= 0 && ix + 1 < dim) ? 1.f : 0.f;
        const float vy0 = (iy >= 0 && iy < dim) ? 1.f : 0.f;
        const float vy1 = (iy + 1 >= 0 && iy + 1 < dim) ? 1.f : 0.f;
        offs[r][s][0] = (startL + iy0 * dim + ix0) * (NB_HD * 2);
        offs[r][s][1] = (startL + iy0 * dim + ix1) * (NB_HD * 2);
        offs[r][s][2] = (startL + iy1 * dim + ix0) * (NB_HD * 2);
        offs[r][s][3] = (startL + iy1 * dim + ix1) * (NB_HD * 2);
        wts[r][s][0] = w * (1.f - lx) * (1.f - ly) * vx0 * vy0;
        wts[r][s][1] = w * lx * (1.f - ly) * vx1 * vy0;
        wts[r][s][2] = w * (1.f - lx) * ly * vx0 * vy1;
        wts[r][s][3] = w * lx * ly * vx1 * vy1;
    }
    __syncthreads();

    const int r = t >> 4, hd2 = t & 15;
    const char* slab = reinterpret_cast<const char*>(vt)
                     + (size_t)(b * NB_NH + h) * NB_S * (NB_HD * 2);
    const int byo = hd2 * 4;
    float ax = 0.f, ay = 0.f;
#pragma unroll
    for (int s = 0; s < 16; ++s) {
        const int4   o = *reinterpret_cast<const int4*>(&offs[r][s][0]);
        const float4 w = *reinterpret_cast<const float4*>(&wts[r][s][0]);
        union { unsigned u; _Float16 h[2]; } c0, c1, c2, c3;
        c0.u = *reinterpret_cast<const unsigned*>(slab + (o.x + byo));
        c1.u = *reinterpret_cast<const unsigned*>(slab + (o.y + byo));
        c2.u = *reinterpret_cast<const unsigned*>(slab + (o.z + byo));
        c3.u = *reinterpret_cast<const unsigned*>(slab + (o.w + byo));
        ax = fmaf(w.x, (float)c0.h[0], ax); ay = fmaf(w.x, (float)c0.h[1], ay);
        ax = fmaf(w.y, (float)c1.h[0], ax); ay = fmaf(w.y, (float)c1.h[1], ay);
        ax = fmaf(w.z, (float)c2.h[0], ax); ay = fmaf(w.z, (float)c2.h[1], ay);
        ax = fmaf(w.w, (float)c3.h[0], ax); ay = fmaf(w.w, (float)c3.h[1], ay);
    }
    union { unsigned u; _Float16 h[2]; } p;
    p.h[0] = (_Float16)ax; p.h[1] = (_Float16)ay;
    *reinterpret_cast<unsigned*>(tmp + (size_t)(row0 + r) * 256 + h * 32 + hd2 * 2) = p.u;
}

// ---------------------------------------------------------------------------
// oproj: out = tmp @ Wo + bo. R9 version (proven): BM=64, BN=128 2-split,
// BK=32, 2-buf, coalesced reg staging.
// ---------------------------------------------------------------------------
__global__ __launch_bounds__(256) void k_oproj_mm(const _Float16* __restrict__ tmp,
                                                  const _Float16* __restrict__ Wot,
                                                  const float* __restrict__ bo,
                                                  float* __restrict__ out)
{
    __shared__ __align__(16) _Float16 Ao[2][4 * ASTR];
    __shared__ __align__(16) _Float16 Bh[2][4 * BSTRO];
    const int t = threadIdx.x;
    const int lane = t & 63, w = t >> 6;
    const int bid = blockIdx.x;
    const int n0 = (bid & 1) * 128;
    const int row0 = (bid >> 1) * 64;

    const int arr = t >> 2;   // A row 0..63
    const int acl = t & 3;    // A oct
    const int bnn = t >> 2;   // B n within 64-half
    const int bcl = t & 3;    // B oct

    const _Float16* gA0 = tmp + (size_t)min(row0 + arr, MQ - 1) * 256 + acl * 8;
    const _Float16* gB0 = Wot + (size_t)(n0 + bnn) * 256 + bcl * 8;
    const _Float16* gB1 = Wot + (size_t)(n0 + 64 + bnn) * 256 + bcl * 8;

    uint4 ar0, br0, br1;
#define LOADT(kt) { ar0 = *reinterpret_cast<const uint4*>(gA0 + (kt) * 32); \
                    br0 = *reinterpret_cast<const uint4*>(gB0 + (kt) * 32); \
                    br1 = *reinterpret_cast<const uint4*>(gB1 + (kt) * 32); }

    LOADT(0);

    f32x4 acc[4][2];
#pragma unroll
    for (int fr = 0; fr < 4; ++fr)
#pragma unroll
        for (int fc = 0; fc < 2; ++fc) acc[fr][fc] = (f32x4){0.f, 0.f, 0.f, 0.f};

    const int rowb = lane & 15;
    const int kq = lane >> 4;
    int buf = 0;
#pragma unroll
    for (int kt = 0; kt < 8; ++kt) {
        *reinterpret_cast<uint4*>(&Ao[buf][acl * ASTR + arr * 8])        = ar0;
        *reinterpret_cast<uint4*>(&Bh[buf][bcl * BSTRO + bnn * 8])        = br0;
        *reinterpret_cast<uint4*>(&Bh[buf][bcl * BSTRO + (64 + bnn) * 8]) = br1;
        if (kt < 7) LOADT(kt + 1);
        __syncthreads();

        half8 af[4], bf[2];
#pragma unroll
        for (int fr = 0; fr < 4; ++fr)
            af[fr] = *reinterpret_cast<const half8*>(&Ao[buf][kq * ASTR + (fr * 16 + rowb) * 8]);
#pragma unroll
        for (int fc = 0; fc < 2; ++fc)
            bf[fc] = *reinterpret_cast<const half8*>(&Bh[buf][kq * BSTRO + (w * 32 + fc * 16 + rowb) * 8]);
#pragma unroll
        for (int fr = 0; fr < 4; ++fr)
#pragma unroll
            for (int fc = 0; fc < 2; ++fc)
                acc[fr][fc] = __builtin_amdgcn_mfma_f32_16x16x32_f16(af[fr], bf[fc], acc[fr][fc], 0, 0, 0);
        buf ^= 1;
    }
#undef LOADT

#pragma unroll
    for (int fc = 0; fc < 2; ++fc) {
        const int n = n0 + w * 32 + fc * 16 + rowb;
        const float bon = bo[n];
#pragma unroll
        for (int fr = 0; fr < 4; ++fr) {
            const f32x4 c = acc[fr][fc];
#pragma unroll
            for (int j = 0; j < 4; ++j) {
                const int m = fr * 16 + (lane >> 4) * 4 + j;
                if (row0 + m < MQ)
                    out[(size_t)(row0 + m) * 256 + n] = c[j] + bon;
            }
        }
    }
}

// ---------------------------------------------------------------------------
extern "C" void kernel_launch(void* const* d_in, const int* in_sizes, int n_in,
                              void* d_out, int out_size, void* d_ws, size_t ws_size,
                              hipStream_t stream)
{
    const float* query = (const float*)d_in[0];
    const float* refp  = (const float*)d_in[1];
    const float* value = (const float*)d_in[2];
    const float* Wv = (const float*)d_in[4];
    const float* bv = (const float*)d_in[5];
    const float* Ws = (const float*)d_in[6];
    const float* bs = (const float*)d_in[7];
    const float* Wa = (const float*)d_in[8];
    const float* ba = (const float*)d_in[9];
    const float* Wo = (const float*)d_in[10];
    const float* bo = (const float*)d_in[11];
    float* out = (float*)d_out;

    char* ws = (char*)d_ws;
    _Float16* vt_h  = (_Float16*)(ws + 0);          // 43520*256*2   = 22,282,240 B
    _Float16* tmp_h = (_Float16*)(ws + 22282240);   // 20000*256*2   = 10,240,000 B
    _Float16* Wvt   = (_Float16*)(ws + 32522240);   //                   131,072 B
    _Float16* Wsat  = (_Float16*)(ws + 32653312);   //                   196,608 B
    _Float16* Wot   = (_Float16*)(ws + 32849920);   //                   131,072 B
    float*    sxg   = (float*)   (ws + 32980992);   // 20000*128*4   = 10,240,000 B
    float*    syg   = (float*)   (ws + 43220992);
    float*    swg   = (float*)   (ws + 53460992);   // ends 63,700,992

    hipLaunchKernelGGL(k_prepw, dim3(896), dim3(256), 0, stream,
                       Wv, Ws, Wa, Wo, Wvt, Wsat, Wot);
    hipLaunchKernelGGL(k_front, dim3(NVB3 + NCO3 + NCL3), dim3(256), 0, stream,
                       value, query, Wvt, Wsat, refp, bv, bs, ba,
                       vt_h, sxg, syg, swg);
    hipLaunchKernelGGL(k_gather, dim3(NB_B * NB_Q / 16 * NB_NH), dim3(256), 0, stream,
                       vt_h, sxg, syg, swg, tmp_h);
    hipLaunchKernelGGL(k_oproj_mm, dim3(MQB * 2), dim3(256), 0, stream,
                       tmp_h, Wot, bo, out);
}

// Round 15
// 99.055 us; speedup vs baseline: 1.4719x; 1.3097x over previous
//
#include <hip/hip_runtime.h>

#define NB_B  2
#define NB_Q  10000
#define NB_D  256
#define NB_NH 8
#define NB_NL 4
#define NB_NP 4
#define NB_HD 32
#define NB_S  21760   // 128*128 + 64*64 + 32*32 + 16*16
#define MQ    20000   // B*Q
#define MQB   313     // ceil(20000/64)
#define NVB   1360    // (B*S/64)*2  vproj blocks
#define NCB   939     // MQB*3       coords blocks

#define ASTR  536     // A oct stride in halfs (R9 pad)
#define GSTR  32768   // tiled-weight group stride in halfs: 8kt*4oct*128n*8

typedef _Float16 half8 __attribute__((ext_vector_type(8)));
typedef float f32x4 __attribute__((ext_vector_type(4)));

// ---------------------------------------------------------------------------
// Prep: transpose + fp16-convert weights into per-K-step tiled layout:
//   W_tiled[g][kt][oct][nl][8]   (g = n>>7, nl = n&127, k = kt*32+oct*8+off)
// so GEMM B staging is a contiguous thread-indexed copy.
// ---------------------------------------------------------------------------
__device__ __forceinline__ size_t wtile_idx(int n, int k) {
    return (size_t)(n >> 7) * GSTR + (k >> 5) * 4096 + ((k >> 3) & 3) * 1024
         + (n & 127) * 8 + (k & 7);
}

__global__ __launch_bounds__(256) void k_prepw(const float* __restrict__ Wv,
                                               const float* __restrict__ Ws,
                                               const float* __restrict__ Wa,
                                               const float* __restrict__ Wo,
                                               _Float16* __restrict__ Wvt,
                                               _Float16* __restrict__ Wsat,
                                               _Float16* __restrict__ Wot)
{
    const int k = threadIdx.x;
    const int nc = blockIdx.x;
    if (nc < 256) {
        Wvt[wtile_idx(nc, k)] = (_Float16)Wv[k * 256 + nc];
    } else if (nc < 640) {
        const int n = nc - 256;
        const float v = (n < 256) ? Ws[k * 256 + n] : Wa[k * 128 + (n - 256)];
        Wsat[wtile_idx(n, k)] = (_Float16)v;
    } else {
        const int n = nc - 640;
        Wot[wtile_idx(n, k)] = (_Float16)Wo[k * 256 + n];
    }
}

// ---------------------------------------------------------------------------
// k_front: co-launched vproj [0,NVB) + coords [NVB,NVB+NCB).
// BM=64, BN=128, BK=32, 2-buf LDS, reg prefetch-1 (R9-proven schedule).
//   A: coalesced rows (thread -> row t>>3, float4-col t&7), cvt->fp16 in regs
//   B: PRE-TILED weights -> 2 contiguous uint4/thread, linear LDS write
// ---------------------------------------------------------------------------
__global__ __launch_bounds__(256) void k_front(const float* __restrict__ value,
                                               const float* __restrict__ query,
                                               const _Float16* __restrict__ Wvt,
                                               const _Float16* __restrict__ Wsat,
                                               const float* __restrict__ refp,
                                               const float* __restrict__ bv,
                                               const float* __restrict__ bs,
                                               const float* __restrict__ ba,
                                               _Float16* __restrict__ vt,
                                               float* __restrict__ sx,
                                               float* __restrict__ sy,
                                               float* __restrict__ sw)
{
    __shared__ __align__(16) _Float16 Ah[2][4 * ASTR];   // 2 x 4288 B
    __shared__ __align__(16) _Float16 Bh[2][4096];       // 2 x 8192 B  [oct][nl][8]
    __shared__ float rp[64][8];                          // 2 KB (coords only)

    const int t = threadIdx.x;
    const int lane = t & 63, w = t >> 6;
    const int bid = blockIdx.x;
    const bool isv = (bid < NVB);

    int row0, n0;
    const float* Asrc;
    const _Float16* Bt;
    if (isv) {
        n0 = (bid & 1) * 128;
        row0 = (bid >> 1) * 64;
        Asrc = value;
        Bt = Wvt + (size_t)(bid & 1) * GSTR;
    } else {
        const int cid = bid - NVB;
        const int g = cid % 3;
        n0 = g * 128;
        row0 = (cid / 3) * 64;
        Asrc = query;
        Bt = Wsat + (size_t)g * GSTR;
        const int i0 = row0 * 8 + t;
        rp[t >> 3][t & 7] = refp[min(i0, MQ * 8 - 1)];
        const int i1 = i0 + 256;
        rp[32 + (t >> 3)][t & 7] = refp[min(i1, MQ * 8 - 1)];
    }

    // A coalesced staging map (R9)
    const int arr = t >> 3;   // A row within 32-row half
    const int acl = t & 7;    // A float4 col within 32-k tile

    const float* gA0;
    const float* gA1;
    {
        int r0i = row0 + arr, r1i = row0 + 32 + arr;
        if (!isv) { r0i = min(r0i, MQ - 1); r1i = min(r1i, MQ - 1); }
        gA0 = Asrc + (size_t)r0i * 256 + acl * 4;
        gA1 = Asrc + (size_t)r1i * 256 + acl * 4;
    }

    float4 ar0, ar1;
    uint4  br0, br1;
#define LOADT(kt) { ar0 = *reinterpret_cast<const float4*>(gA0 + (kt) * 32); \
                    ar1 = *reinterpret_cast<const float4*>(gA1 + (kt) * 32); \
                    br0 = *reinterpret_cast<const uint4*>(Bt + (kt) * 4096 + t * 8);        \
                    br1 = *reinterpret_cast<const uint4*>(Bt + (kt) * 4096 + 2048 + t * 8); }

    LOADT(0);

    f32x4 acc[4][2];
#pragma unroll
    for (int fr = 0; fr < 4; ++fr)
#pragma unroll
        for (int fc = 0; fc < 2; ++fc) acc[fr][fc] = (f32x4){0.f, 0.f, 0.f, 0.f};

    const int rowb = lane & 15;
    const int kq = lane >> 4;
    const int awoff = (acl >> 1) * ASTR + arr * 8 + (acl & 1) * 4;
    int buf = 0;
#pragma unroll
    for (int kt = 0; kt < 8; ++kt) {
        {
            union { _Float16 h[4]; uint2 u; } p0, p1;
            p0.h[0] = (_Float16)ar0.x; p0.h[1] = (_Float16)ar0.y;
            p0.h[2] = (_Float16)ar0.z; p0.h[3] = (_Float16)ar0.w;
            p1.h[0] = (_Float16)ar1.x; p1.h[1] = (_Float16)ar1.y;
            p1.h[2] = (_Float16)ar1.z; p1.h[3] = (_Float16)ar1.w;
            *reinterpret_cast<uint2*>(&Ah[buf][awoff])          = p0.u;
            *reinterpret_cast<uint2*>(&Ah[buf][awoff + 32 * 8]) = p1.u;  // +32 rows
            *reinterpret_cast<uint4*>(&Bh[buf][t * 8])        = br0;
            *reinterpret_cast<uint4*>(&Bh[buf][2048 + t * 8]) = br1;
        }
        if (kt < 7) LOADT(kt + 1);
        __syncthreads();

        half8 af[4], bf[2];
#pragma unroll
        for (int fr = 0; fr < 4; ++fr)
            af[fr] = *reinterpret_cast<const half8*>(&Ah[buf][kq * ASTR + (fr * 16 + rowb) * 8]);
#pragma unroll
        for (int fc = 0; fc < 2; ++fc)
            bf[fc] = *reinterpret_cast<const half8*>(&Bh[buf][kq * 1024 + (w * 32 + fc * 16 + rowb) * 8]);
#pragma unroll
        for (int fr = 0; fr < 4; ++fr)
#pragma unroll
            for (int fc = 0; fc < 2; ++fc)
                acc[fr][fc] = __builtin_amdgcn_mfma_f32_16x16x32_f16(af[fr], bf[fc], acc[fr][fc], 0, 0, 0);
        buf ^= 1;
    }
#undef LOADT

    // ---- epilogues (identical to R9) ----
    if (isv) {
        const int b = (row0 >= NB_S) ? 1 : 0;
        const int sb = row0 - b * NB_S;
#pragma unroll
        for (int fc = 0; fc < 2; ++fc) {
            const int n = n0 + w * 32 + fc * 16 + rowb;
            const int h = n >> 5, hd = n & 31;
            const float bvn = bv[n];
#pragma unroll
            for (int fr = 0; fr < 4; ++fr) {
                const f32x4 c = acc[fr][fc];
#pragma unroll
                for (int j = 0; j < 4; ++j) {
                    const int m = fr * 16 + (lane >> 4) * 4 + j;
                    vt[((size_t)((b * NB_NH + h) * NB_S + (sb + m)) << 5) + hd] = (_Float16)(c[j] + bvn);
                }
            }
        }
    } else if (n0 < 256) {
#pragma unroll
        for (int fc = 0; fc < 2; ++fc) {
            const int n = n0 + w * 32 + fc * 16 + rowb;
            const int si = n >> 1, xy = n & 1;
            const int l = (n >> 3) & 3;
            const float dim = (float)(128 >> l);
            const float bsv = bs[n];
            float* dst = xy ? sy : sx;
#pragma unroll
            for (int fr = 0; fr < 4; ++fr) {
                const f32x4 c = acc[fr][fc];
#pragma unroll
                for (int j = 0; j < 4; ++j) {
                    const int m = fr * 16 + (lane >> 4) * 4 + j;
                    if (row0 + m < MQ) {
                        const float coord = rp[m][l * 2 + xy] * dim + (c[j] + bsv) - 0.5f;
                        dst[(size_t)(row0 + m) * 128 + si] = coord;
                    }
                }
            }
        }
    } else {
#pragma unroll
        for (int fc = 0; fc < 2; ++fc) {
            const int col = w * 32 + fc * 16 + rowb;
            const float bav = ba[col];
#pragma unroll
            for (int fr = 0; fr < 4; ++fr) {
                const f32x4 c = acc[fr][fc];
#pragma unroll
                for (int j = 0; j < 4; ++j) {
                    const int m = fr * 16 + (lane >> 4) * 4 + j;
                    float v = c[j] + bav;
                    float vm = v;
                    vm = fmaxf(vm, __shfl_xor(vm, 1));
                    vm = fmaxf(vm, __shfl_xor(vm, 2));
                    vm = fmaxf(vm, __shfl_xor(vm, 4));
                    vm = fmaxf(vm, __shfl_xor(vm, 8));
                    const float e = expf(v - vm);
                    float s = e;
                    s += __shfl_xor(s, 1);
                    s += __shfl_xor(s, 2);
                    s += __shfl_xor(s, 4);
                    s += __shfl_xor(s, 8);
                    if (row0 + m < MQ)
                        sw[(size_t)(row0 + m) * 128 + col] = e / s;
                }
            }
        }
    }
}

// ---------------------------------------------------------------------------
// gather: block = (16 queries, 1 head); head = blockIdx.x & 7 (XCD locality).
// ---------------------------------------------------------------------------
__global__ __launch_bounds__(256) void k_gather(const _Float16* __restrict__ vt,
                                                const float* __restrict__ sx,
                                                const float* __restrict__ sy,
                                                const float* __restrict__ sw,
                                                _Float16* __restrict__ tmp)
{
    __shared__ int   offs[16][16][4];
    __shared__ float wts[16][16][4];
    const int t = threadIdx.x;
    const int gid = blockIdx.x;
    const int h = gid & 7;
    const int row0 = (gid >> 3) * 16;
    const int b = (row0 >= NB_Q) ? 1 : 0;

    {
        const int r = t >> 4, s = t & 15;
        const size_t ci = (size_t)(row0 + r) * 128 + h * 16 + s;
        const float x = sx[ci], y = sy[ci], w = sw[ci];
        const int l = s >> 2;
        const int dim = 128 >> l;
        const int startL = (l == 0) ? 0 : (l == 1) ? 16384 : (l == 2) ? 20480 : 21504;
        const float x0f = floorf(x), y0f = floorf(y);
        const float lx = x - x0f, ly = y - y0f;
        const int ix = (int)x0f, iy = (int)y0f;
        const int ix0 = min(max(ix, 0), dim - 1), ix1 = min(max(ix + 1, 0), dim - 1);
        const int iy0 = min(max(iy, 0), dim - 1), iy1 = min(max(iy + 1, 0), dim - 1);
        const float vx0 = (ix >= 0 && ix < dim) ? 1.f : 0.f;
        const float vx1 = (ix + 1 >= 0 && ix + 1 < dim) ? 1.f : 0.f;
        const float vy0 = (iy >= 0 && iy < dim) ? 1.f : 0.f;
        const float vy1 = (iy + 1 >= 0 && iy + 1 < dim) ? 1.f : 0.f;
        offs[r][s][0] = (startL + iy0 * dim + ix0) * (NB_HD * 2);
        offs[r][s][1] = (startL + iy0 * dim + ix1) * (NB_HD * 2);
        offs[r][s][2] = (startL + iy1 * dim + ix0) * (NB_HD * 2);
        offs[r][s][3] = (startL + iy1 * dim + ix1) * (NB_HD * 2);
        wts[r][s][0] = w * (1.f - lx) * (1.f - ly) * vx0 * vy0;
        wts[r][s][1] = w * lx * (1.f - ly) * vx1 * vy0;
        wts[r][s][2] = w * (1.f - lx) * ly * vx0 * vy1;
        wts[r][s][3] = w * lx * ly * vx1 * vy1;
    }
    __syncthreads();

    const int r = t >> 4, hd2 = t & 15;
    const char* slab = reinterpret_cast<const char*>(vt)
                     + (size_t)(b * NB_NH + h) * NB_S * (NB_HD * 2);
    const int byo = hd2 * 4;
    float ax = 0.f, ay = 0.f;
#pragma unroll
    for (int s = 0; s < 16; ++s) {
        const int4   o = *reinterpret_cast<const int4*>(&offs[r][s][0]);
        const float4 w = *reinterpret_cast<const float4*>(&wts[r][s][0]);
        union { unsigned u; _Float16 h[2]; } c0, c1, c2, c3;
        c0.u = *reinterpret_cast<const unsigned*>(slab + (o.x + byo));
        c1.u = *reinterpret_cast<const unsigned*>(slab + (o.y + byo));
        c2.u = *reinterpret_cast<const unsigned*>(slab + (o.z + byo));
        c3.u = *reinterpret_cast<const unsigned*>(slab + (o.w + byo));
        ax = fmaf(w.x, (float)c0.h[0], ax); ay = fmaf(w.x, (float)c0.h[1], ay);
        ax = fmaf(w.y, (float)c1.h[0], ax); ay = fmaf(w.y, (float)c1.h[1], ay);
        ax = fmaf(w.z, (float)c2.h[0], ax); ay = fmaf(w.z, (float)c2.h[1], ay);
        ax = fmaf(w.w, (float)c3.h[0], ax); ay = fmaf(w.w, (float)c3.h[1], ay);
    }
    union { unsigned u; _Float16 h[2]; } p;
    p.h[0] = (_Float16)ax; p.h[1] = (_Float16)ay;
    *reinterpret_cast<unsigned*>(tmp + (size_t)(row0 + r) * 256 + h * 32 + hd2 * 2) = p.u;
}

// ---------------------------------------------------------------------------
// oproj: out = tmp @ Wo + bo. R9 schedule; B pre-tiled (2 contiguous uint4).
// ---------------------------------------------------------------------------
__global__ __launch_bounds__(256) void k_oproj_mm(const _Float16* __restrict__ tmp,
                                                  const _Float16* __restrict__ Wot,
                                                  const float* __restrict__ bo,
                                                  float* __restrict__ out)
{
    __shared__ __align__(16) _Float16 Ao[2][4 * ASTR];
    __shared__ __align__(16) _Float16 Bh[2][4096];
    const int t = threadIdx.x;
    const int lane = t & 63, w = t >> 6;
    const int bid = blockIdx.x;
    const int n0 = (bid & 1) * 128;
    const int row0 = (bid >> 1) * 64;
    const _Float16* Bt = Wot + (size_t)(bid & 1) * GSTR;

    const int arr = t >> 2;   // A row 0..63
    const int acl = t & 3;    // A oct

    const _Float16* gA0 = tmp + (size_t)min(row0 + arr, MQ - 1) * 256 + acl * 8;

    uint4 ar0, br0, br1;
#define LOADT(kt) { ar0 = *reinterpret_cast<const uint4*>(gA0 + (kt) * 32); \
                    br0 = *reinterpret_cast<const uint4*>(Bt + (kt) * 4096 + t * 8);        \
                    br1 = *reinterpret_cast<const uint4*>(Bt + (kt) * 4096 + 2048 + t * 8); }

    LOADT(0);

    f32x4 acc[4][2];
#pragma unroll
    for (int fr = 0; fr < 4; ++fr)
#pragma unroll
        for (int fc = 0; fc < 2; ++fc) acc[fr][fc] = (f32x4){0.f, 0.f, 0.f, 0.f};

    const int rowb = lane & 15;
    const int kq = lane >> 4;
    int buf = 0;
#pragma unroll
    for (int kt = 0; kt < 8; ++kt) {
        *reinterpret_cast<uint4*>(&Ao[buf][acl * ASTR + arr * 8]) = ar0;
        *reinterpret_cast<uint4*>(&Bh[buf][t * 8])        = br0;
        *reinterpret_cast<uint4*>(&Bh[buf][2048 + t * 8]) = br1;
        if (kt < 7) LOADT(kt + 1);
        __syncthreads();

        half8 af[4], bf[2];
#pragma unroll
        for (int fr = 0; fr < 4; ++fr)
            af[fr] = *reinterpret_cast<const half8*>(&Ao[buf][kq * ASTR + (fr * 16 + rowb) * 8]);
#pragma unroll
        for (int fc = 0; fc < 2; ++fc)
            bf[fc] = *reinterpret_cast<const half8*>(&Bh[buf][kq * 1024 + (w * 32 + fc * 16 + rowb) * 8]);
#pragma unroll
        for (int fr = 0; fr < 4; ++fr)
#pragma unroll
            for (int fc = 0; fc < 2; ++fc)
                acc[fr][fc] = __builtin_amdgcn_mfma_f32_16x16x32_f16(af[fr], bf[fc], acc[fr][fc], 0, 0, 0);
        buf ^= 1;
    }
#undef LOADT

#pragma unroll
    for (int fc = 0; fc < 2; ++fc) {
        const int n = n0 + w * 32 + fc * 16 + rowb;
        const float bon = bo[n];
#pragma unroll
        for (int fr = 0; fr < 4; ++fr) {
            const f32x4 c = acc[fr][fc];
#pragma unroll
            for (int j = 0; j < 4; ++j) {
                const int m = fr * 16 + (lane >> 4) * 4 + j;
                if (row0 + m < MQ)
                    out[(size_t)(row0 + m) * 256 + n] = c[j] + bon;
            }
        }
    }
}

// ---------------------------------------------------------------------------
extern "C" void kernel_launch(void* const* d_in, const int* in_sizes, int n_in,
                              void* d_out, int out_size, void* d_ws, size_t ws_size,
                              hipStream_t stream)
{
    const float* query = (const float*)d_in[0];
    const float* refp  = (const float*)d_in[1];
    const float* value = (const float*)d_in[2];
    const float* Wv = (const float*)d_in[4];
    const float* bv = (const float*)d_in[5];
    const float* Ws = (const float*)d_in[6];
    const float* bs = (const float*)d_in[7];
    const float* Wa = (const float*)d_in[8];
    const float* ba = (const float*)d_in[9];
    const float* Wo = (const float*)d_in[10];
    const float* bo = (const float*)d_in[11];
    float* out = (float*)d_out;

    char* ws = (char*)d_ws;
    _Float16* vt_h  = (_Float16*)(ws + 0);          // 43520*256*2   = 22,282,240 B
    _Float16* tmp_h = (_Float16*)(ws + 22282240);   // 20000*256*2   = 10,240,000 B
    _Float16* Wvt   = (_Float16*)(ws + 32522240);   //                   131,072 B
    _Float16* Wsat  = (_Float16*)(ws + 32653312);   //                   196,608 B
    _Float16* Wot   = (_Float16*)(ws + 32849920);   //                   131,072 B
    float*    sxg   = (float*)   (ws + 32980992);   // 20000*128*4   = 10,240,000 B
    float*    syg   = (float*)   (ws + 43220992);
    float*    swg   = (float*)   (ws + 53460992);   // ends 63,700,992

    hipLaunchKernelGGL(k_prepw, dim3(896), dim3(256), 0, stream,
                       Wv, Ws, Wa, Wo, Wvt, Wsat, Wot);
    hipLaunchKernelGGL(k_front, dim3(NVB + NCB), dim3(256), 0, stream,
                       value, query, Wvt, Wsat, refp, bv, bs, ba,
                       vt_h, sxg, syg, swg);
    hipLaunchKernelGGL(k_gather, dim3(NB_B * NB_Q / 16 * NB_NH), dim3(256), 0, stream,
                       vt_h, sxg, syg, swg, tmp_h);
    hipLaunchKernelGGL(k_oproj_mm, dim3(MQB * 2), dim3(256), 0, stream,
                       tmp_h, Wot, bo, out);
}